// Round 7
// baseline (147.799 us; speedup 1.0000x reference)
//
#include <hip/hip_runtime.h>

#define NROWS  32768
#define DIM    64
#define KCODES 1024
#define NELEM  (NROWS * DIM)      // 2097152
#define NBLK_B 512                // vq_out blocks
#define RPB_B  64                 // rows per vq_out block

typedef float v2f __attribute__((ext_vector_type(2)));
typedef float v4f __attribute__((ext_vector_type(4)));

// Guaranteed-codegen packed FMA (round-6 lesson: the compiler materializes
// (v2f){s,s} splats and float4->v2f unpacks as v_movs, ~3x VALU bloat).
// op_sel makes the w broadcast an instruction modifier:
//  lo: acc += {xp.lo*wp.lo, xp.hi*wp.lo}   (src1 lo for both halves)
//  hi: acc += {xp.lo*wp.hi, xp.hi*wp.hi}   (src1 hi for both halves)
__device__ __forceinline__ void pk_fma_lo(v2f& acc, v2f xp, v2f wp) {
  asm("v_pk_fma_f32 %0, %1, %2, %0 op_sel:[0,0,0] op_sel_hi:[1,0,1]"
      : "+v"(acc) : "v"(xp), "v"(wp));
}
__device__ __forceinline__ void pk_fma_hi(v2f& acc, v2f xp, v2f wp) {
  asm("v_pk_fma_f32 %0, %1, %2, %0 op_sel:[0,1,0] op_sel_hi:[1,1,1]"
      : "+v"(acc) : "v"(xp), "v"(wp));
}

// numpy pairwise sum-of-squares over a 64-float row: 8 accumulators, r[k]
// sums v[8i+k] over i, combine ((r0+r1)+(r2+r3))+((r4+r5)+(r6+r7)).
// contract(off): numpy squares into a temp then sums — no FMA fusion.
// Verified bit-exact rounds 1-6 (absmax 0.0).
__device__ __forceinline__ float np_sumsq_f4(const float4* __restrict__ p) {
#pragma clang fp contract(off)
  float4 a = p[0], b = p[1];
  float r0 = a.x * a.x, r1 = a.y * a.y, r2 = a.z * a.z, r3 = a.w * a.w;
  float r4 = b.x * b.x, r5 = b.y * b.y, r6 = b.z * b.z, r7 = b.w * b.w;
#pragma unroll
  for (int i = 1; i < 8; ++i) {
    a = p[2 * i]; b = p[2 * i + 1];
    r0 += a.x * a.x; r1 += a.y * a.y; r2 += a.z * a.z; r3 += a.w * a.w;
    r4 += b.x * b.x; r5 += b.y * b.y; r6 += b.z * b.z; r7 += b.w * b.w;
  }
  return ((r0 + r1) + (r2 + r3)) + ((r4 + r5) + (r6 + r7));
}

// Prep: per-row ||x||^2, per-code ||e||^2 (numpy pairwise rounding), zero
// loss/cnt. Grid 128 x 256.
__global__ __launch_bounds__(256) void vq_prep(const float* __restrict__ x,
                                               const float* __restrict__ w,
                                               float* __restrict__ sxv,
                                               float* __restrict__ se,
                                               double* __restrict__ loss,
                                               unsigned int* __restrict__ cnt) {
  const int t = blockIdx.x * 256 + threadIdx.x;
  if (t == 0) { *loss = 0.0; *cnt = 0u; }
  sxv[t] = np_sumsq_f4((const float4*)(x + (size_t)t * DIM));
  if (t < KCODES) se[t] = np_sumsq_f4((const float4*)(w + (size_t)t * DIM));
}

// vq_dist: 128x128-tile GEMM over K=64, asm-pk inner loop.
//  LDS xst: k-major, PAIR-swizzled: pair p (rows 2p,2p+1) of k stored at
//    pslot = p ^ (4*(k&15)); reads of pairs 4R..4R+3 at k become 4 ds_read_b64
//    from base 4*(R^(k&15)) (+0,1,2,3) -> 4 unique addrs, 16-way broadcast,
//    4 distinct bank groups: conflict-free, x-pairs are native reg pairs.
//  LDS wst: code-major k-batched float4, slot = f4 ^ ((c>>3)&7): reads spread
//    16 unique addrs over 8 bank groups = 2-way (free, m136); quad subpairs
//    (w_k0,w_k1)/(w_k2,w_k3) feed pk_fma lo/hi op_sel variants.
//  Thread (C=t&15, R=t>>4): rows 8R..8R+7 (4 v2f pairs), codes 8C..8C+7.
//  acc[4][8] v2f = 64 VGPRs. Per f4-step: 8 b128 w + 16 b64 x + 128 pk_fma.
//  All swizzle XORs fold with compile-time k -> ~3 VALU addr per k.
// d = fmaf(-2, dot, fl(sx+se[c])) — bit-exact vs ref's fl(fl(sx+se)-fl(2dot));
// dot is an FMA chain (order-insensitivity verified rounds 1-6, absmax 0.0).
// Argmin: ascending-code strict-< per thread -> u64 (dist<<32|code) min
// across threads (LDS) -> per-chunk slot; vq_out does cross-chunk min.
__global__ __launch_bounds__(256, 2) void vq_dist(const float* __restrict__ x,
                                                  const float* __restrict__ w,
                                                  const float* __restrict__ sxv,
                                                  const float* __restrict__ seg,
                                                  unsigned long long* __restrict__ keys) {
  __shared__ float xst[64 * 128];   // 32 KB, k-major pair-swizzled
  __shared__ float wst[128 * 64];   // 32 KB, code-major f4-swizzled
  const int t = threadIdx.x;
  const int rg = blockIdx.x >> 3;
  const int chunk = blockIdx.x & 7;
  const int row0 = rg * 128;
  const int c0 = chunk * 128;

  // ---- stage tiles ----
  {
    const float4* xg = (const float4*)x + (size_t)row0 * 16;
    const float4* wg = (const float4*)w + (size_t)c0 * 16;
    float4* wst4 = (float4*)wst;
#pragma unroll
    for (int i = 0; i < 8; ++i) {
      const int g = t + 256 * i;           // 0..2047
      const int rr = g >> 4, f4 = g & 15;
      float4 q = xg[g];                    // row rr, k = 4*f4..4*f4+3
      const int p = rr >> 1, o = rr & 1;
#pragma unroll
      for (int j = 0; j < 4; ++j) {
        const int k = 4 * f4 + j;
        const int pslot = p ^ ((k & 15) << 2);
        const float val = (j == 0) ? q.x : (j == 1) ? q.y : (j == 2) ? q.z : q.w;
        xst[k * 128 + ((pslot << 1) | o)] = val;
      }
      float4 u = wg[g];                    // code rr, k-group f4
      wst4[rr * 16 + (f4 ^ ((rr >> 3) & 7))] = u;
    }
  }
  __syncthreads();

  const int C = t & 15;        // code-group: codes 8C..8C+7
  const int R = t >> 4;        // row-block:  rows  8R..8R+7
  const int C7 = C & 7;

  v2f acc[4][8];
#pragma unroll
  for (int u = 0; u < 4; ++u)
#pragma unroll
    for (int oc = 0; oc < 8; ++oc) acc[u][oc] = (v2f){0.f, 0.f};

  const v2f* xs2 = (const v2f*)xst;
  const v4f* ws4 = (const v4f*)wst;
  const int wbase = C << 7;    // 128*C in float4 units

#pragma unroll
  for (int f4 = 0; f4 < 16; ++f4) {
    v4f wq[8];
    const int wo = wbase + (f4 ^ C7);
#pragma unroll
    for (int oc = 0; oc < 8; ++oc) wq[oc] = ws4[wo + (oc << 4)];
#pragma unroll
    for (int kk = 0; kk < 4; ++kk) {
      const int k = 4 * f4 + kk;
      const int xb = (k << 6) + ((R ^ (k & 15)) << 2);
      v2f xp0 = xs2[xb + 0];   // rows 8R+0,8R+1 at k (swizzle cancels)
      v2f xp1 = xs2[xb + 1];
      v2f xp2 = xs2[xb + 2];
      v2f xp3 = xs2[xb + 3];
#pragma unroll
      for (int oc = 0; oc < 8; ++oc) {
        v2f wp = (kk < 2) ? __builtin_shufflevector(wq[oc], wq[oc], 0, 1)
                          : __builtin_shufflevector(wq[oc], wq[oc], 2, 3);
        if ((kk & 1) == 0) {
          pk_fma_lo(acc[0][oc], xp0, wp); pk_fma_lo(acc[1][oc], xp1, wp);
          pk_fma_lo(acc[2][oc], xp2, wp); pk_fma_lo(acc[3][oc], xp3, wp);
        } else {
          pk_fma_hi(acc[0][oc], xp0, wp); pk_fma_hi(acc[1][oc], xp1, wp);
          pk_fma_hi(acc[2][oc], xp2, wp); pk_fma_hi(acc[3][oc], xp3, wp);
        }
      }
    }
  }

  // ---- epilogue: per-thread best key per row (ascending codes) ----
  float sxr[8], sev[8];
#pragma unroll
  for (int j = 0; j < 8; ++j) sxr[j] = sxv[row0 + 8 * R + j];
#pragma unroll
  for (int oc = 0; oc < 8; ++oc) sev[oc] = seg[c0 + 8 * C + oc];

  unsigned long long bk[8];
#pragma unroll
  for (int u = 0; u < 4; ++u) {
#pragma unroll
    for (int h = 0; h < 2; ++h) {
      const float sx = sxr[2 * u + h];
      unsigned long long best = ~0ull;
#pragma unroll
      for (int oc = 0; oc < 8; ++oc) {
        const float dot = h ? acc[u][oc].y : acc[u][oc].x;
        const float d = fmaf(-2.0f, dot, sx + sev[oc]);
        const unsigned long long key =
            ((unsigned long long)__float_as_uint(d) << 32) |
            (unsigned int)(c0 + 8 * C + oc);
        if (key < best) best = key;
      }
      bk[2 * u + h] = best;
    }
  }

  // ---- cross-thread per-row reduce (reuse xst after barrier) ----
  __syncthreads();
  unsigned long long* kred = (unsigned long long*)xst;   // 128*17*8 = 17 KB
#pragma unroll
  for (int j = 0; j < 8; ++j) kred[(8 * R + j) * 17 + C] = bk[j];
  __syncthreads();
  if (t < 128) {
    unsigned long long mn = kred[t * 17];
#pragma unroll
    for (int q = 1; q < 16; ++q) {
      const unsigned long long kq = kred[t * 17 + q];
      if (kq < mn) mn = kq;
    }
    keys[((size_t)(row0 + t) << 3) | chunk] = mn;
  }
}

// vq_out: 8-way key min -> index; indices (as float), STE quantized output
// x + fl(w - x) (bit-exact ref forward), fp64 loss shuffle-reduce + one
// atomic/block; last block (device counter) finalizes commitment loss.
// Unchanged from rounds 4-6 (verified absmax 0.0).
__global__ __launch_bounds__(256) void vq_out(const float* __restrict__ x,
                                              const float* __restrict__ w,
                                              const unsigned long long* __restrict__ keys,
                                              float* __restrict__ outq,
                                              float* __restrict__ outidx,
                                              double* __restrict__ loss,
                                              unsigned int* __restrict__ cnt,
                                              float* __restrict__ outloss) {
  __shared__ int sidx[RPB_B];
  __shared__ double part[4];
  const int b = blockIdx.x, t = threadIdx.x;

  if (t < RPB_B) {
    const int row = b * RPB_B + t;
    const unsigned long long* kr = keys + ((size_t)row << 3);
    unsigned long long mn = kr[0];
#pragma unroll
    for (int i = 1; i < 8; ++i) { unsigned long long k = kr[i]; if (k < mn) mn = k; }
    const int idx = (int)(unsigned int)(mn & 0xFFFFFFFFull);
    outidx[row] = (float)idx;
    sidx[t] = idx;
  }
  __syncthreads();

  double acc = 0.0;
  const float4* x4 = (const float4*)x;
  float4* o4 = (float4*)outq;
#pragma unroll
  for (int i = 0; i < 4; ++i) {
    const int e = i * 256 + t;
    const int rl = e >> 4;
    const int d4 = e & 15;
    const size_t gofs = ((size_t)b * RPB_B + rl) * 16 + d4;
    float4 xvv = x4[gofs];
    const float4* wr = (const float4*)(w + (size_t)sidx[rl] * DIM);
    float4 wv = wr[d4];
    float tx = wv.x - xvv.x, ty = wv.y - xvv.y;
    float tz = wv.z - xvv.z, tw = wv.w - xvv.w;
    float4 q;
    q.x = xvv.x + tx; q.y = xvv.y + ty;   // ref STE: x + fl(q - x)
    q.z = xvv.z + tz; q.w = xvv.w + tw;
    o4[gofs] = q;
    acc += (double)tx * tx + (double)ty * ty + (double)tz * tz + (double)tw * tw;
  }

#pragma unroll
  for (int s = 32; s > 0; s >>= 1) acc += __shfl_down(acc, s, 64);
  if ((t & 63) == 0) part[t >> 6] = acc;
  __syncthreads();
  if (t == 0) {
    atomicAdd(loss, (part[0] + part[1]) + (part[2] + part[3]));
    __threadfence();
    unsigned int old = atomicAdd(cnt, 1u);
    if (old == NBLK_B - 1) {
      double L = atomicAdd(loss, 0.0);   // all adds happened-before
      *outloss = 0.5f * (float)(L / (double)NELEM);
    }
  }
}

extern "C" void kernel_launch(void* const* d_in, const int* in_sizes, int n_in,
                              void* d_out, int out_size, void* d_ws, size_t ws_size,
                              hipStream_t stream) {
  const float* x = (const float*)d_in[0];   // inputs (32,64,32,32) fp32
  const float* w = (const float*)d_in[1];   // weight (1024,64) fp32

  float* outq    = (float*)d_out;           // [0, 2097152)
  float* outidx  = outq + NELEM;            // [2097152, +32768)
  float* outloss = outidx + NROWS;          // [2129920]

  char* wsb = (char*)d_ws;
  double* loss = (double*)wsb;                                     // @0
  unsigned int* cnt = (unsigned int*)(wsb + 64);                   // @64
  float* sxv = (float*)(wsb + 4096);                               // 128 KB
  float* se  = (float*)(wsb + 4096 + 131072);                      // 4 KB
  unsigned long long* keys = (unsigned long long*)(wsb + 139264);  // 2 MB

  hipLaunchKernelGGL(vq_prep, dim3(128),  dim3(256), 0, stream,
                     x, w, sxv, se, loss, cnt);
  hipLaunchKernelGGL(vq_dist, dim3(2048), dim3(256), 0, stream,
                     x, w, sxv, se, keys);
  hipLaunchKernelGGL(vq_out,  dim3(NBLK_B), dim3(256), 0, stream,
                     x, w, keys, outq, outidx, loss, cnt, outloss);
}